// Round 16
// baseline (1001.760 us; speedup 1.0000x reference)
//
#include <hip/hip_runtime.h>
#include <hip/hip_bf16.h>

#define DD 32
#define GG 96   // 3*DD

typedef __attribute__((ext_vector_type(8))) short bf16x8;
typedef __attribute__((ext_vector_type(4))) float f32x4;

__device__ __forceinline__ float frcp(float x){ return __builtin_amdgcn_rcpf(x); }
__device__ __forceinline__ float fsig(float x){
    float e = __expf(-x);
    return frcp(1.0f + e);
}
__device__ __forceinline__ float ftanh(float x){
    float ax = fabsf(x);
    float e  = __expf(-2.0f * ax);
    float t  = (1.0f - e) * frcp(1.0f + e);
    return copysignf(t, x);
}
__device__ __forceinline__ short f2bf(float f){
    union { float f; unsigned u; } v; v.f = f;
    unsigned r = v.u + 0x7fffu + ((v.u >> 16) & 1u);   // RNE
    return (short)(r >> 16);
}
__device__ __forceinline__ float bf2f(short s){
    union { unsigned u; float f; } v; v.u = ((unsigned)(unsigned short)s) << 16;
    return v.f;
}
__device__ __forceinline__ void split2(float x, short& hi, short& lo){
    hi = f2bf(x);
    lo = f2bf(x - bf2f(hi));
}
__device__ __forceinline__ f32x4 splat4(float x){ f32x4 v = { x, x, x, x }; return v; }

#define MFMA3(acc, ah, al, bh, bl) do { \
    acc = __builtin_amdgcn_mfma_f32_16x16x32_bf16(ah, bh, acc, 0, 0, 0); \
    acc = __builtin_amdgcn_mfma_f32_16x16x32_bf16(al, bh, acc, 0, 0, 0); \
    acc = __builtin_amdgcn_mfma_f32_16x16x32_bf16(ah, bl, acc, 0, 0, 0); \
} while (0)

// ---------------- setup kernels ----------------

__global__ void zero_ints_kernel(int* a, int n){
    int i = blockIdx.x * blockDim.x + threadIdx.x;
    if (i < n) a[i] = 0;
}

__global__ void init_states_kernel(const float* __restrict__ cap,
                                   const float* __restrict__ traffic, const float* __restrict__ packets,
                                   const float* __restrict__ tdp,
                                   float* __restrict__ ls, short* __restrict__ lsbh, short* __restrict__ lsbl,
                                   float* __restrict__ ps, int n_links, int n_paths){
    int i = blockIdx.x * blockDim.x + threadIdx.x;
    int nl = n_links * DD;
    if (i < nl){
        int l = i >> 5, d = i & 31;
        float v = (d == 0) ? cap[l] : 0.0f;
        ls[i] = v;
        short hi, lo; split2(v, hi, lo);
        lsbh[i] = hi; lsbl[i] = lo;
        return;
    }
    int j = i - nl;
    if (j >= n_paths * DD) return;
    int p = j >> 5, d = j & 31;
    float v = 0.0f;
    if (d == 0) v = traffic[p];
    else if (d == 1) v = packets[p];
    else if (d < 14) v = tdp[p * 12 + (d - 2)];
    ps[j] = v;
}

__global__ void meta_kernel(const int* __restrict__ path_ids, const int* __restrict__ seqp,
                            const int* __restrict__ seql, int* __restrict__ start,
                            int* __restrict__ lenp, int* __restrict__ lcount, int E){
    int e = blockIdx.x * blockDim.x + threadIdx.x;
    if (e >= E) return;
    int p = path_ids[e];
    int s = seqp[e];
    if (s == 0) start[p] = e;
    if (e == E - 1 || path_ids[e + 1] != p) lenp[p] = s + 1;
    atomicAdd(&lcount[seql[e]], 1);
}

__global__ void bhist_block_kernel(const int* __restrict__ lenp, int* __restrict__ bcnt,
                                   int* __restrict__ bh, int n_paths){
    __shared__ int h[16];
    if (threadIdx.x < 16) h[threadIdx.x] = 0;
    __syncthreads();
    int p = blockIdx.x * 256 + threadIdx.x;
    if (p < n_paths) atomicAdd(&h[lenp[p] - 1], 1);
    __syncthreads();
    if (threadIdx.x < 16){
        bh[blockIdx.x * 16 + threadIdx.x] = h[threadIdx.x];
        atomicAdd(&bcnt[threadIdx.x], h[threadIdx.x]);
    }
}

__global__ void bscan2_kernel(const int* __restrict__ bcnt, const int* __restrict__ bh,
                              int* __restrict__ bb, int nblk){
    __shared__ int base[16];
    if (threadIdx.x == 0){
        int run = 0;
        for (int i = 0; i < 16; i++){ base[i] = run; run += bcnt[i]; }
    }
    __syncthreads();
    int i = threadIdx.x;
    if (i < 16){
        int run = base[i];
        for (int blk = 0; blk < nblk; ++blk){
            bb[blk * 16 + i] = run;
            run += bh[blk * 16 + i];
        }
    }
}

__global__ void bscatter2_kernel(const int* __restrict__ lenp, const int* __restrict__ bb,
                                 int* __restrict__ order, int n_paths){
    __shared__ int h[16];
    if (threadIdx.x < 16) h[threadIdx.x] = 0;
    __syncthreads();
    int p = blockIdx.x * 256 + threadIdx.x;
    if (p < n_paths){
        int b = lenp[p] - 1;
        int r = atomicAdd(&h[b], 1);
        order[bb[blockIdx.x * 16 + b] + r] = p;
    }
}

__global__ __launch_bounds__(1024) void scan_kernel(const int* __restrict__ cnt, int* __restrict__ off, int n){
    __shared__ int psh[1025];
    int tid = threadIdx.x;
    int chunk = (n + 1023) / 1024;
    int b = tid * chunk, e = min(b + chunk, n);
    int s = 0;
    for (int i = b; i < e; ++i) s += cnt[i];
    psh[tid + 1] = s;
    if (tid == 0) psh[0] = 0;
    __syncthreads();
    for (int ofs = 1; ofs < 1024; ofs <<= 1){
        int v = (tid + 1 >= ofs) ? psh[tid + 1 - ofs] : 0;
        __syncthreads();
        psh[tid + 1] += v;
        __syncthreads();
    }
    int run = psh[tid];
    for (int i = b; i < e; ++i){ off[i] = run; run += cnt[i]; }
    if (b < n && e == n) off[n] = run;
}

__global__ void fillpbl_kernel(const int* __restrict__ seql, const int* __restrict__ p2l,
                               const int* __restrict__ loff, int* __restrict__ lfill,
                               int* __restrict__ pbl, int E){
    int e = blockIdx.x * blockDim.x + threadIdx.x;
    if (e >= E) return;
    int l = seql[e];
    int pos = loff[l] + atomicAdd(&lfill[l], 1);
    pbl[pos] = p2l[e];
}

// fused weight packing (same fragment tables as R10/R11).
__global__ void pack_all_kernel(const float* __restrict__ pK, const float* __restrict__ pRK,
                                const float* __restrict__ lK, const float* __restrict__ lRK,
                                const float* __restrict__ w1, const float* __restrict__ w2,
                                short* __restrict__ gth, short* __restrict__ gtl,
                                short* __restrict__ rth, short* __restrict__ rtl){
    int t0 = blockIdx.x * blockDim.x + threadIdx.x;
    if (t0 < 4 * 6 * 64){
        int t = t0;
        int lane = t & 63;
        int jt = (t >> 6) % 6;
        int mat = t / (6 * 64);
        const float* W = (mat == 0) ? pK : (mat == 1) ? pRK : (mat == 2) ? lK : lRK;
        int n = lane & 15, g = lane >> 4;
        for (int i = 0; i < 8; i++){
            float w = W[(g * 8 + i) * GG + jt * 16 + n];
            short hi, lo; split2(w, hi, lo);
            gth[(size_t)t * 8 + i] = hi;
            gtl[(size_t)t * 8 + i] = lo;
        }
        return;
    }
    int t = t0 - 4 * 6 * 64;
    if (t >= 144 * 64) return;
    int lane = t & 63;
    int f = t >> 6;
    int n = lane & 15, g = lane >> 4;
    for (int i = 0; i < 8; i++){
        float w;
        if (f < 16) w = w1[(g * 8 + i) * 256 + f * 16 + n];
        else {
            int ff = f - 16, kc = ff >> 4, jt = ff & 15;
            w = w2[(kc * 32 + g * 8 + i) * 256 + jt * 16 + n];
        }
        short hi, lo; split2(w, hi, lo);
        rth[(size_t)t * 8 + i] = hi;
        rtl[(size_t)t * 8 + i] = lo;
    }
}

// ---------------- swapped-operand MFMA GRU pieces (validated R11-R15) ----------------
template<bool MASK>
__device__ __forceinline__ void gru_gates(const f32x4 accZR[4], const f32x4 accXC[2], const f32x4 accHC[2],
                                          float hD[2][4], int la, int t)
{
    #pragma unroll
    for (int tt = 0; tt < 2; tt++){
        #pragma unroll
        for (int r = 0; r < 4; r++){
            float z = fsig(accZR[tt][r]);
            float rr = fsig(accZR[2 + tt][r]);
            float c = ftanh(accXC[tt][r] + rr * accHC[tt][r]);
            float hn = z * hD[tt][r] + (1.0f - z) * c;
            if (MASK) hD[tt][r] = (t < la) ? hn : hD[tt][r];
            else      hD[tt][r] = hn;
        }
    }
}

__device__ __forceinline__ void hD_to_bfrag(const float hD[2][4], int l15, int g,
                                            bf16x8& bh, bf16x8& bl){
    unsigned pk0[4], pk1[4];
    #pragma unroll
    for (int r = 0; r < 4; r++){
        short hi, lo;
        split2(hD[0][r], hi, lo);
        pk0[r] = (((unsigned)(unsigned short)hi) << 16) | (unsigned)(unsigned short)lo;
        split2(hD[1][r], hi, lo);
        pk1[r] = (((unsigned)(unsigned short)hi) << 16) | (unsigned)(unsigned short)lo;
    }
    bool hiTT = ((g >> 1) & 1);
    #pragma unroll
    for (int i = 0; i < 8; i++){
        int src = l15 + 16 * ((2 * g + (i >> 2)) & 3);
        unsigned v0 = (unsigned)__shfl((int)pk0[i & 3], src, 64);
        unsigned v1 = (unsigned)__shfl((int)pk1[i & 3], src, 64);
        unsigned v = hiTT ? v1 : v0;
        bh[i] = (short)(v >> 16);
        bl[i] = (short)(v & 0xffffu);
    }
}

__device__ __forceinline__ void load_bias4(const float* __restrict__ bias, int g,
                                           f32x4 bZR[4], f32x4 bXC[2], f32x4 bHC[2]){
    #pragma unroll
    for (int jt = 0; jt < 4; jt++)
        #pragma unroll
        for (int r = 0; r < 4; r++)
            bZR[jt][r] = bias[jt * 16 + 4 * g + r] + bias[GG + jt * 16 + 4 * g + r];
    #pragma unroll
    for (int u = 0; u < 2; u++)
        #pragma unroll
        for (int r = 0; r < 4; r++){
            bXC[u][r] = bias[(4 + u) * 16 + 4 * g + r];
            bHC[u][r] = bias[GG + (4 + u) * 16 + 4 * g + r];
        }
}

// ---------------- path GRU: non-persistent, descending-length launch (HW LPT) — R14, unchanged ----------------
__global__ __launch_bounds__(256, 1) void path_gru_kernel(
    const short* __restrict__ lsbh, const short* __restrict__ lsbl, float* __restrict__ ps,
    const int* __restrict__ l2p, const int* __restrict__ start,
    const int* __restrict__ lenp, const int* __restrict__ order,
    const short* __restrict__ gth, const short* __restrict__ gtl,
    const float* __restrict__ bias, int n_paths, int n_waves)
{
    int tid = threadIdx.x;
    int warp = tid >> 6;
    int lane = tid & 63;
    int l15 = lane & 15, g = lane >> 4;

    int gw = blockIdx.x * 4 + warp;
    if (gw >= n_waves) return;
    int base16 = (n_waves - 1 - gw) * 16;     // longest chunks first (LPT by launch order)

    bf16x8 wKh[6], wKl[6], wRKh[6], wRKl[6];
    #pragma unroll
    for (int jt = 0; jt < 6; jt++){
        wKh[jt]  = *(const bf16x8*)(gth + ((size_t)((0 * 6 + jt) * 64 + lane)) * 8);
        wKl[jt]  = *(const bf16x8*)(gtl + ((size_t)((0 * 6 + jt) * 64 + lane)) * 8);
        wRKh[jt] = *(const bf16x8*)(gth + ((size_t)((1 * 6 + jt) * 64 + lane)) * 8);
        wRKl[jt] = *(const bf16x8*)(gtl + ((size_t)((1 * 6 + jt) * 64 + lane)) * 8);
    }
    f32x4 bZR[4], bXC[2], bHC[2];
    load_bias4(bias, g, bZR, bXC, bHC);

    int aidx = base16 + l15;
    bool va = (aidx < n_paths);
    int pa = order[min(aidx, n_paths - 1)];
    int s0 = start[pa];
    int la_c = lenp[pa];
    int la = va ? la_c : 0;
    int maxlen = __shfl(la_c, 15);

    float hD[2][4];
    {
        float4 h0 = *(const float4*)(ps + (size_t)pa * DD + 4 * g);
        float4 h1 = *(const float4*)(ps + (size_t)pa * DD + 16 + 4 * g);
        hD[0][0] = h0.x; hD[0][1] = h0.y; hD[0][2] = h0.z; hD[0][3] = h0.w;
        hD[1][0] = h1.x; hD[1][1] = h1.y; hD[1][2] = h1.z; hD[1][3] = h1.w;
    }

    bf16x8 hfh, hfl;
    hD_to_bfrag(hD, l15, g, hfh, hfl);

    bf16x8 xfh, xfl;
    {
        int lk = l2p[s0];
        xfh = *reinterpret_cast<const bf16x8*>(lsbh + (size_t)lk * DD + g * 8);
        xfl = *reinterpret_cast<const bf16x8*>(lsbl + (size_t)lk * DD + g * 8);
    }

    for (int t = 0; t < maxlen; ++t){
        bf16x8 nxh, nxl;
        int tn = t + 1;
        if (tn < maxlen){
            int e = s0 + max(min(tn, la - 1), 0);
            int lk = l2p[e];
            nxh = *reinterpret_cast<const bf16x8*>(lsbh + (size_t)lk * DD + g * 8);
            nxl = *reinterpret_cast<const bf16x8*>(lsbl + (size_t)lk * DD + g * 8);
        }

        f32x4 accZR[4], accXC[2], accHC[2];
        #pragma unroll
        for (int jt = 0; jt < 4; jt++){
            f32x4 a = bZR[jt];
            MFMA3(a, wKh[jt],  wKl[jt],  xfh, xfl);
            MFMA3(a, wRKh[jt], wRKl[jt], hfh, hfl);
            accZR[jt] = a;
        }
        #pragma unroll
        for (int u = 0; u < 2; u++){
            f32x4 ax = bXC[u];
            MFMA3(ax, wKh[4 + u], wKl[4 + u], xfh, xfl);
            accXC[u] = ax;
            f32x4 ah = bHC[u];
            MFMA3(ah, wRKh[4 + u], wRKl[4 + u], hfh, hfl);
            accHC[u] = ah;
        }

        gru_gates<true>(accZR, accXC, accHC, hD, la, t);
        hD_to_bfrag(hD, l15, g, hfh, hfl);

        xfh = nxh; xfl = nxl;
    }

    if (va){
        float4 h0 = { hD[0][0], hD[0][1], hD[0][2], hD[0][3] };
        float4 h1 = { hD[1][0], hD[1][1], hD[1][2], hD[1][3] };
        *(float4*)(ps + (size_t)pa * DD + 4 * g) = h0;
        *(float4*)(ps + (size_t)pa * DD + 16 + 4 * g) = h1;
    }
}

// ---------------- fused segment-sum + link GRU, 4-wave strided gather — R15, unchanged ----------------
__global__ __launch_bounds__(256, 1) void link_fused_kernel(
    const float* __restrict__ ps, const int* __restrict__ loff, const int* __restrict__ pbl,
    float* __restrict__ ls, short* __restrict__ lsbh, short* __restrict__ lsbl,
    const short* __restrict__ gth, const short* __restrict__ gtl,
    const float* __restrict__ bias, int n_links)
{
    __shared__ __align__(16) float part[3][16][36];

    int tid = threadIdx.x;
    int warp = tid >> 6;
    int lane = tid & 63;
    int l15 = lane & 15, g = lane >> 4;

    int base16 = blockIdx.x * 16;
    if (base16 >= n_links) return;

    int di = base16 + l15;
    bool va = (di < n_links);
    int pa = min(di, n_links - 1);

    float4 s0v = {0,0,0,0}, s1v = {0,0,0,0};
    {
        int b = loff[pa], e = loff[pa + 1];
        for (int k = b + warp; k < e; k += 4){
            const float4* pr = (const float4*)(ps + (size_t)pbl[k] * DD) + g * 2;
            float4 v0 = pr[0], v1 = pr[1];
            s0v.x += v0.x; s0v.y += v0.y; s0v.z += v0.z; s0v.w += v0.w;
            s1v.x += v1.x; s1v.y += v1.y; s1v.z += v1.z; s1v.w += v1.w;
        }
    }

    if (warp > 0){
        *(float4*)(&part[warp - 1][l15][g * 8])     = s0v;
        *(float4*)(&part[warp - 1][l15][g * 8 + 4]) = s1v;
    }
    __syncthreads();
    if (warp != 0) return;

    #pragma unroll
    for (int w = 0; w < 3; w++){
        float4 p0 = *(const float4*)(&part[w][l15][g * 8]);
        float4 p1 = *(const float4*)(&part[w][l15][g * 8 + 4]);
        s0v.x += p0.x; s0v.y += p0.y; s0v.z += p0.z; s0v.w += p0.w;
        s1v.x += p1.x; s1v.y += p1.y; s1v.z += p1.z; s1v.w += p1.w;
    }

    bf16x8 wKh[6], wKl[6], wRKh[6], wRKl[6];
    #pragma unroll
    for (int jt = 0; jt < 6; jt++){
        wKh[jt]  = *(const bf16x8*)(gth + ((size_t)((2 * 6 + jt) * 64 + lane)) * 8);
        wKl[jt]  = *(const bf16x8*)(gtl + ((size_t)((2 * 6 + jt) * 64 + lane)) * 8);
        wRKh[jt] = *(const bf16x8*)(gth + ((size_t)((3 * 6 + jt) * 64 + lane)) * 8);
        wRKl[jt] = *(const bf16x8*)(gtl + ((size_t)((3 * 6 + jt) * 64 + lane)) * 8);
    }
    f32x4 bZR[4], bXC[2], bHC[2];
    load_bias4(bias, g, bZR, bXC, bHC);

    float hD[2][4];
    {
        float4 h0 = *(const float4*)(ls + (size_t)pa * DD + 4 * g);
        float4 h1 = *(const float4*)(ls + (size_t)pa * DD + 16 + 4 * g);
        hD[0][0] = h0.x; hD[0][1] = h0.y; hD[0][2] = h0.z; hD[0][3] = h0.w;
        hD[1][0] = h1.x; hD[1][1] = h1.y; hD[1][2] = h1.z; hD[1][3] = h1.w;
    }
    bf16x8 hfh = *reinterpret_cast<const bf16x8*>(lsbh + (size_t)pa * DD + g * 8);
    bf16x8 hfl = *reinterpret_cast<const bf16x8*>(lsbl + (size_t)pa * DD + g * 8);

    bf16x8 xfh, xfl;
    {
        float xs[8] = { s0v.x, s0v.y, s0v.z, s0v.w, s1v.x, s1v.y, s1v.z, s1v.w };
        #pragma unroll
        for (int i = 0; i < 8; i++){
            short hi, lo; split2(xs[i], hi, lo);
            xfh[i] = hi; xfl[i] = lo;
        }
    }

    f32x4 accZR[4], accXC[2], accHC[2];
    #pragma unroll
    for (int jt = 0; jt < 4; jt++){
        f32x4 a = bZR[jt];
        MFMA3(a, wKh[jt],  wKl[jt],  xfh, xfl);
        MFMA3(a, wRKh[jt], wRKl[jt], hfh, hfl);
        accZR[jt] = a;
    }
    #pragma unroll
    for (int u = 0; u < 2; u++){
        f32x4 ax = bXC[u];
        MFMA3(ax, wKh[4 + u], wKl[4 + u], xfh, xfl);
        accXC[u] = ax;
        f32x4 ah = bHC[u];
        MFMA3(ah, wRKh[4 + u], wRKl[4 + u], hfh, hfl);
        accHC[u] = ah;
    }
    gru_gates<false>(accZR, accXC, accHC, hD, 0, 0);

    if (va){
        float4 h0 = { hD[0][0], hD[0][1], hD[0][2], hD[0][3] };
        float4 h1 = { hD[1][0], hD[1][1], hD[1][2], hD[1][3] };
        *(float4*)(ls + (size_t)pa * DD + 4 * g) = h0;
        *(float4*)(ls + (size_t)pa * DD + 16 + 4 * g) = h1;
        short hs[8], lws[8];
        #pragma unroll
        for (int r = 0; r < 4; r++){ split2(hD[0][r], hs[r], lws[r]); split2(hD[1][r], hs[4 + r], lws[4 + r]); }
        *(short4*)(lsbh + (size_t)pa * DD + 4 * g)      = make_short4(hs[0], hs[1], hs[2], hs[3]);
        *(short4*)(lsbh + (size_t)pa * DD + 16 + 4 * g) = make_short4(hs[4], hs[5], hs[6], hs[7]);
        *(short4*)(lsbl + (size_t)pa * DD + 4 * g)      = make_short4(lws[0], lws[1], lws[2], lws[3]);
        *(short4*)(lsbl + (size_t)pa * DD + 16 + 4 * g) = make_short4(lws[4], lws[5], lws[6], lws[7]);
    }
}

// ---------------- readout MLP (MFMA split-bf16): 32 -> 256 relu -> 256 relu -> 1 ----------------
// R15 analysis: 6250 waves x 256KB of L2 weight-fragment reads = 1.6 GB/dispatch ->
// L2-BW bound (>=46us at 35 TB/s). Fix: 32 paths/wave (two 16-path A-groups) so each
// loaded weight fragment feeds TWO MFMA3 calls -> L2 traffic halves. acc2 doubles
// (~200 VGPR, fine without min-waves clamp; throughput-bound, not latency-bound).
__global__ __launch_bounds__(256) void readout_kernel(
    const float* __restrict__ ps,
    const short* __restrict__ rth, const short* __restrict__ rtl,
    const float* __restrict__ b1, const float* __restrict__ b2,
    const float* __restrict__ w3, const float* __restrict__ b3,
    float* __restrict__ out, int n_paths)
{
    __shared__ __align__(16) float hT[4][2][16 * 68];

    int tid = threadIdx.x;
    int warp = tid >> 6;
    int lane = tid & 63;
    int l15 = lane & 15, g = lane >> 4;
    int pbase = blockIdx.x * 128 + warp * 32;

    // two x A-fragments (2 x 16 paths x 32 dims), hi/lo
    bf16x8 xh[2], xl[2];
    #pragma unroll
    for (int q = 0; q < 2; q++){
        int prow = min(pbase + q * 16 + l15, n_paths - 1);
        const float* xp = ps + (size_t)prow * DD + g * 8;
        #pragma unroll
        for (int i = 0; i < 8; i++){ short hi, lo; split2(xp[i], hi, lo); xh[q][i] = hi; xl[q][i] = lo; }
    }

    f32x4 acc2[2][16];
    #pragma unroll
    for (int q = 0; q < 2; q++)
        #pragma unroll
        for (int jt = 0; jt < 16; jt++) acc2[q][jt] = splat4(b2[jt * 16 + l15]);

    #pragma unroll 1
    for (int c = 0; c < 4; c++){
        // L1: 4 col-tiles of h1 (cols c*64 .. c*64+63), both groups share each fragment
        #pragma unroll
        for (int u = 0; u < 4; u++){
            int jt = c * 4 + u;
            bf16x8 wh = *(const bf16x8*)(rth + (size_t)(jt * 64 + lane) * 8);
            bf16x8 wl = *(const bf16x8*)(rtl + (size_t)(jt * 64 + lane) * 8);
            float b1v = b1[jt * 16 + l15];
            #pragma unroll
            for (int q = 0; q < 2; q++){
                f32x4 a = splat4(b1v);
                MFMA3(a, xh[q], xl[q], wh, wl);
                #pragma unroll
                for (int r = 0; r < 4; r++)
                    hT[warp][q][(g * 4 + r) * 68 + u * 16 + l15] = fmaxf(a[r], 0.0f);
            }
        }
        // transpose: read A-fragments of this 64-col chunk (wave-private LDS)
        bf16x8 ah[2][2], al[2][2];
        #pragma unroll
        for (int q = 0; q < 2; q++)
            #pragma unroll
            for (int kc2 = 0; kc2 < 2; kc2++){
                const float* hr = hT[warp][q] + l15 * 68 + kc2 * 32 + g * 8;
                #pragma unroll
                for (int i = 0; i < 8; i++){ short hi, lo; split2(hr[i], hi, lo); ah[q][kc2][i] = hi; al[q][kc2][i] = lo; }
            }
        // L2: accumulate this K-chunk into all 16 output tiles, fragments shared
        #pragma unroll
        for (int jt = 0; jt < 16; jt++){
            #pragma unroll
            for (int kc2 = 0; kc2 < 2; kc2++){
                int f = 16 + (c * 2 + kc2) * 16 + jt;
                bf16x8 wh = *(const bf16x8*)(rth + (size_t)(f * 64 + lane) * 8);
                bf16x8 wl = *(const bf16x8*)(rtl + (size_t)(f * 64 + lane) * 8);
                #pragma unroll
                for (int q = 0; q < 2; q++)
                    MFMA3(acc2[q][jt], ah[q][kc2], al[q][kc2], wh, wl);
            }
        }
    }

    // w3 dot + reduction across the 16-lane col group, both groups
    float part[2][4] = {{0,0,0,0},{0,0,0,0}};
    #pragma unroll
    for (int jt = 0; jt < 16; jt++){
        float w3v = w3[jt * 16 + l15];
        #pragma unroll
        for (int q = 0; q < 2; q++)
            #pragma unroll
            for (int r = 0; r < 4; r++)
                part[q][r] = fmaf(fmaxf(acc2[q][jt][r], 0.0f), w3v, part[q][r]);
    }
    #pragma unroll
    for (int ofs = 1; ofs < 16; ofs <<= 1)
        #pragma unroll
        for (int q = 0; q < 2; q++)
            #pragma unroll
            for (int r = 0; r < 4; r++)
                part[q][r] += __shfl_xor(part[q][r], ofs);

    if (l15 == 0){
        float b3v = b3[0];
        #pragma unroll
        for (int q = 0; q < 2; q++)
            #pragma unroll
            for (int r = 0; r < 4; r++){
                int p = pbase + q * 16 + g * 4 + r;
                if (p < n_paths) out[p] = part[q][r] + b3v;
            }
    }
}

extern "C" void kernel_launch(void* const* d_in, const int* in_sizes, int n_in,
                              void* d_out, int out_size, void* d_ws, size_t ws_size,
                              hipStream_t stream)
{
    const float* capacity = (const float*)d_in[0];
    const float* traffic  = (const float*)d_in[1];
    const float* packets  = (const float*)d_in[2];
    const float* tdp      = (const float*)d_in[3];
    const float* pK  = (const float*)d_in[4];
    const float* pRK = (const float*)d_in[5];
    const float* pB  = (const float*)d_in[6];
    const float* lK  = (const float*)d_in[7];
    const float* lRK = (const float*)d_in[8];
    const float* lB  = (const float*)d_in[9];
    const float* w1  = (const float*)d_in[10];
    const float* b1  = (const float*)d_in[11];
    const float* w2  = (const float*)d_in[12];
    const float* b2  = (const float*)d_in[13];
    const float* w3  = (const float*)d_in[14];
    const float* b3  = (const float*)d_in[15];
    const int* l2p      = (const int*)d_in[16];
    const int* path_ids = (const int*)d_in[17];
    const int* seqp     = (const int*)d_in[18];
    const int* p2l      = (const int*)d_in[19];
    const int* seql     = (const int*)d_in[20];
    int n_links = in_sizes[0];
    int n_paths = in_sizes[1];
    int E       = in_sizes[16];
    float* out = (float*)d_out;

    char* w = (char*)d_ws;
    auto carve = [&](size_t bytes) -> void* {
        void* r = (void*)w;
        w += (bytes + 255) & ~(size_t)255;
        return r;
    };
    int nblk = (n_paths + 255) / 256;
    float* ls    = (float*)carve((size_t)n_links * DD * 4);
    short* lsbh  = (short*)carve((size_t)n_links * DD * 2);
    short* lsbl  = (short*)carve((size_t)n_links * DD * 2);
    float* ps    = (float*)carve((size_t)n_paths * DD * 4);
    int* start   = (int*)carve((size_t)n_paths * 4);
    int* lenp    = (int*)carve((size_t)n_paths * 4);
    int* order   = (int*)carve((size_t)n_paths * 4);
    int* loff    = (int*)carve((size_t)(n_links + 1) * 4);
    int* pbl     = (int*)carve((size_t)E * 4);
    short* gth   = (short*)carve((size_t)4 * 6 * 64 * 8 * 2);
    short* gtl   = (short*)carve((size_t)4 * 6 * 64 * 8 * 2);
    short* rth   = (short*)carve((size_t)144 * 64 * 8 * 2);
    short* rtl   = (short*)carve((size_t)144 * 64 * 8 * 2);
    int* bh      = (int*)carve((size_t)nblk * 16 * 4);
    int* bb      = (int*)carve((size_t)nblk * 16 * 4);
    int* izero   = (int*)carve(((size_t)2 * n_links + 16) * 4);
    int* lcount  = izero;
    int* lfill   = izero + n_links;
    int* bcnt    = izero + 2 * n_links;

    const int TB = 256;
    int nz = 2 * n_links + 16;
    zero_ints_kernel<<<(nz + TB - 1) / TB, TB, 0, stream>>>(izero, nz);
    init_states_kernel<<<(((n_links + n_paths) * DD) + TB - 1) / TB, TB, 0, stream>>>(
        capacity, traffic, packets, tdp, ls, lsbh, lsbl, ps, n_links, n_paths);
    meta_kernel<<<(E + TB - 1) / TB, TB, 0, stream>>>(path_ids, seqp, seql, start, lenp, lcount, E);
    bhist_block_kernel<<<nblk, 256, 0, stream>>>(lenp, bcnt, bh, n_paths);
    bscan2_kernel<<<1, 64, 0, stream>>>(bcnt, bh, bb, nblk);
    bscatter2_kernel<<<nblk, 256, 0, stream>>>(lenp, bb, order, n_paths);
    scan_kernel<<<1, 1024, 0, stream>>>(lcount, loff, n_links);
    fillpbl_kernel<<<(E + TB - 1) / TB, TB, 0, stream>>>(seql, p2l, loff, lfill, pbl, E);
    pack_all_kernel<<<((4 * 6 * 64 + 144 * 64) + TB - 1) / TB, TB, 0, stream>>>(
        pK, pRK, lK, lRK, w1, w2, gth, gtl, rth, rtl);

    int n_waves = (n_paths + 15) / 16;
    int pg_blocks = (n_waves + 3) / 4;
    int lg_blocks = (n_links + 15) / 16;      // one block (4 waves) per 16 links

    for (int it = 0; it < 8; ++it){
        path_gru_kernel<<<pg_blocks, 256, 0, stream>>>(lsbh, lsbl, ps, l2p, start, lenp, order,
                                                       gth, gtl, pB, n_paths, n_waves);
        link_fused_kernel<<<lg_blocks, 256, 0, stream>>>(ps, loff, pbl, ls, lsbh, lsbl,
                                                         gth, gtl, lB, n_links);
    }
    readout_kernel<<<(n_paths + 127) / 128, 256, 0, stream>>>(ps, rth, rtl, b1, b2, w3, b3, out, n_paths);
}

// Round 17
// 970.353 us; speedup vs baseline: 1.0324x; 1.0324x over previous
//
#include <hip/hip_runtime.h>
#include <hip/hip_bf16.h>

#define DD 32
#define GG 96   // 3*DD

typedef __attribute__((ext_vector_type(8))) short bf16x8;
typedef __attribute__((ext_vector_type(4))) float f32x4;

__device__ __forceinline__ float frcp(float x){ return __builtin_amdgcn_rcpf(x); }
__device__ __forceinline__ float fsig(float x){
    float e = __expf(-x);
    return frcp(1.0f + e);
}
__device__ __forceinline__ float ftanh(float x){
    float ax = fabsf(x);
    float e  = __expf(-2.0f * ax);
    float t  = (1.0f - e) * frcp(1.0f + e);
    return copysignf(t, x);
}
__device__ __forceinline__ short f2bf(float f){
    union { float f; unsigned u; } v; v.f = f;
    unsigned r = v.u + 0x7fffu + ((v.u >> 16) & 1u);   // RNE
    return (short)(r >> 16);
}
__device__ __forceinline__ float bf2f(short s){
    union { unsigned u; float f; } v; v.u = ((unsigned)(unsigned short)s) << 16;
    return v.f;
}
__device__ __forceinline__ void split2(float x, short& hi, short& lo){
    hi = f2bf(x);
    lo = f2bf(x - bf2f(hi));
}
__device__ __forceinline__ f32x4 splat4(float x){ f32x4 v = { x, x, x, x }; return v; }

#define MFMA3(acc, ah, al, bh, bl) do { \
    acc = __builtin_amdgcn_mfma_f32_16x16x32_bf16(ah, bh, acc, 0, 0, 0); \
    acc = __builtin_amdgcn_mfma_f32_16x16x32_bf16(al, bh, acc, 0, 0, 0); \
    acc = __builtin_amdgcn_mfma_f32_16x16x32_bf16(ah, bl, acc, 0, 0, 0); \
} while (0)

// ---------------- setup kernels ----------------

__global__ void zero_ints_kernel(int* a, int n){
    int i = blockIdx.x * blockDim.x + threadIdx.x;
    if (i < n) a[i] = 0;
}

__global__ void init_states_kernel(const float* __restrict__ cap,
                                   const float* __restrict__ traffic, const float* __restrict__ packets,
                                   const float* __restrict__ tdp,
                                   float* __restrict__ ls, short* __restrict__ lsbh, short* __restrict__ lsbl,
                                   float* __restrict__ ps, int n_links, int n_paths){
    int i = blockIdx.x * blockDim.x + threadIdx.x;
    int nl = n_links * DD;
    if (i < nl){
        int l = i >> 5, d = i & 31;
        float v = (d == 0) ? cap[l] : 0.0f;
        ls[i] = v;
        short hi, lo; split2(v, hi, lo);
        lsbh[i] = hi; lsbl[i] = lo;
        return;
    }
    int j = i - nl;
    if (j >= n_paths * DD) return;
    int p = j >> 5, d = j & 31;
    float v = 0.0f;
    if (d == 0) v = traffic[p];
    else if (d == 1) v = packets[p];
    else if (d < 14) v = tdp[p * 12 + (d - 2)];
    ps[j] = v;
}

__global__ void meta_kernel(const int* __restrict__ path_ids, const int* __restrict__ seqp,
                            const int* __restrict__ seql, int* __restrict__ start,
                            int* __restrict__ lenp, int* __restrict__ lcount, int E){
    int e = blockIdx.x * blockDim.x + threadIdx.x;
    if (e >= E) return;
    int p = path_ids[e];
    int s = seqp[e];
    if (s == 0) start[p] = e;
    if (e == E - 1 || path_ids[e + 1] != p) lenp[p] = s + 1;
    atomicAdd(&lcount[seql[e]], 1);
}

__global__ void bhist_block_kernel(const int* __restrict__ lenp, int* __restrict__ bcnt,
                                   int* __restrict__ bh, int n_paths){
    __shared__ int h[16];
    if (threadIdx.x < 16) h[threadIdx.x] = 0;
    __syncthreads();
    int p = blockIdx.x * 256 + threadIdx.x;
    if (p < n_paths) atomicAdd(&h[lenp[p] - 1], 1);
    __syncthreads();
    if (threadIdx.x < 16){
        bh[blockIdx.x * 16 + threadIdx.x] = h[threadIdx.x];
        atomicAdd(&bcnt[threadIdx.x], h[threadIdx.x]);
    }
}

__global__ void bscan2_kernel(const int* __restrict__ bcnt, const int* __restrict__ bh,
                              int* __restrict__ bb, int nblk){
    __shared__ int base[16];
    if (threadIdx.x == 0){
        int run = 0;
        for (int i = 0; i < 16; i++){ base[i] = run; run += bcnt[i]; }
    }
    __syncthreads();
    int i = threadIdx.x;
    if (i < 16){
        int run = base[i];
        for (int blk = 0; blk < nblk; ++blk){
            bb[blk * 16 + i] = run;
            run += bh[blk * 16 + i];
        }
    }
}

__global__ void bscatter2_kernel(const int* __restrict__ lenp, const int* __restrict__ bb,
                                 int* __restrict__ order, int n_paths){
    __shared__ int h[16];
    if (threadIdx.x < 16) h[threadIdx.x] = 0;
    __syncthreads();
    int p = blockIdx.x * 256 + threadIdx.x;
    if (p < n_paths){
        int b = lenp[p] - 1;
        int r = atomicAdd(&h[b], 1);
        order[bb[blockIdx.x * 16 + b] + r] = p;
    }
}

__global__ __launch_bounds__(1024) void scan_kernel(const int* __restrict__ cnt, int* __restrict__ off, int n){
    __shared__ int psh[1025];
    int tid = threadIdx.x;
    int chunk = (n + 1023) / 1024;
    int b = tid * chunk, e = min(b + chunk, n);
    int s = 0;
    for (int i = b; i < e; ++i) s += cnt[i];
    psh[tid + 1] = s;
    if (tid == 0) psh[0] = 0;
    __syncthreads();
    for (int ofs = 1; ofs < 1024; ofs <<= 1){
        int v = (tid + 1 >= ofs) ? psh[tid + 1 - ofs] : 0;
        __syncthreads();
        psh[tid + 1] += v;
        __syncthreads();
    }
    int run = psh[tid];
    for (int i = b; i < e; ++i){ off[i] = run; run += cnt[i]; }
    if (b < n && e == n) off[n] = run;
}

__global__ void fillpbl_kernel(const int* __restrict__ seql, const int* __restrict__ p2l,
                               const int* __restrict__ loff, int* __restrict__ lfill,
                               int* __restrict__ pbl, int E){
    int e = blockIdx.x * blockDim.x + threadIdx.x;
    if (e >= E) return;
    int l = seql[e];
    int pos = loff[l] + atomicAdd(&lfill[l], 1);
    pbl[pos] = p2l[e];
}

// fused weight packing (same fragment tables as R10/R11).
__global__ void pack_all_kernel(const float* __restrict__ pK, const float* __restrict__ pRK,
                                const float* __restrict__ lK, const float* __restrict__ lRK,
                                const float* __restrict__ w1, const float* __restrict__ w2,
                                short* __restrict__ gth, short* __restrict__ gtl,
                                short* __restrict__ rth, short* __restrict__ rtl){
    int t0 = blockIdx.x * blockDim.x + threadIdx.x;
    if (t0 < 4 * 6 * 64){
        int t = t0;
        int lane = t & 63;
        int jt = (t >> 6) % 6;
        int mat = t / (6 * 64);
        const float* W = (mat == 0) ? pK : (mat == 1) ? pRK : (mat == 2) ? lK : lRK;
        int n = lane & 15, g = lane >> 4;
        for (int i = 0; i < 8; i++){
            float w = W[(g * 8 + i) * GG + jt * 16 + n];
            short hi, lo; split2(w, hi, lo);
            gth[(size_t)t * 8 + i] = hi;
            gtl[(size_t)t * 8 + i] = lo;
        }
        return;
    }
    int t = t0 - 4 * 6 * 64;
    if (t >= 144 * 64) return;
    int lane = t & 63;
    int f = t >> 6;
    int n = lane & 15, g = lane >> 4;
    for (int i = 0; i < 8; i++){
        float w;
        if (f < 16) w = w1[(g * 8 + i) * 256 + f * 16 + n];
        else {
            int ff = f - 16, kc = ff >> 4, jt = ff & 15;
            w = w2[(kc * 32 + g * 8 + i) * 256 + jt * 16 + n];
        }
        short hi, lo; split2(w, hi, lo);
        rth[(size_t)t * 8 + i] = hi;
        rtl[(size_t)t * 8 + i] = lo;
    }
}

// ---------------- swapped-operand MFMA GRU pieces (validated R11-R15) ----------------
template<bool MASK>
__device__ __forceinline__ void gru_gates(const f32x4 accZR[4], const f32x4 accXC[2], const f32x4 accHC[2],
                                          float hD[2][4], int la, int t)
{
    #pragma unroll
    for (int tt = 0; tt < 2; tt++){
        #pragma unroll
        for (int r = 0; r < 4; r++){
            float z = fsig(accZR[tt][r]);
            float rr = fsig(accZR[2 + tt][r]);
            float c = ftanh(accXC[tt][r] + rr * accHC[tt][r]);
            float hn = z * hD[tt][r] + (1.0f - z) * c;
            if (MASK) hD[tt][r] = (t < la) ? hn : hD[tt][r];
            else      hD[tt][r] = hn;
        }
    }
}

__device__ __forceinline__ void hD_to_bfrag(const float hD[2][4], int l15, int g,
                                            bf16x8& bh, bf16x8& bl){
    unsigned pk0[4], pk1[4];
    #pragma unroll
    for (int r = 0; r < 4; r++){
        short hi, lo;
        split2(hD[0][r], hi, lo);
        pk0[r] = (((unsigned)(unsigned short)hi) << 16) | (unsigned)(unsigned short)lo;
        split2(hD[1][r], hi, lo);
        pk1[r] = (((unsigned)(unsigned short)hi) << 16) | (unsigned)(unsigned short)lo;
    }
    bool hiTT = ((g >> 1) & 1);
    #pragma unroll
    for (int i = 0; i < 8; i++){
        int src = l15 + 16 * ((2 * g + (i >> 2)) & 3);
        unsigned v0 = (unsigned)__shfl((int)pk0[i & 3], src, 64);
        unsigned v1 = (unsigned)__shfl((int)pk1[i & 3], src, 64);
        unsigned v = hiTT ? v1 : v0;
        bh[i] = (short)(v >> 16);
        bl[i] = (short)(v & 0xffffu);
    }
}

__device__ __forceinline__ void load_bias4(const float* __restrict__ bias, int g,
                                           f32x4 bZR[4], f32x4 bXC[2], f32x4 bHC[2]){
    #pragma unroll
    for (int jt = 0; jt < 4; jt++)
        #pragma unroll
        for (int r = 0; r < 4; r++)
            bZR[jt][r] = bias[jt * 16 + 4 * g + r] + bias[GG + jt * 16 + 4 * g + r];
    #pragma unroll
    for (int u = 0; u < 2; u++)
        #pragma unroll
        for (int r = 0; r < 4; r++){
            bXC[u][r] = bias[(4 + u) * 16 + 4 * g + r];
            bHC[u][r] = bias[GG + (4 + u) * 16 + 4 * g + r];
        }
}

// ---------------- path GRU: non-persistent, descending-length launch (HW LPT) — R14, unchanged ----------------
__global__ __launch_bounds__(256, 1) void path_gru_kernel(
    const short* __restrict__ lsbh, const short* __restrict__ lsbl, float* __restrict__ ps,
    const int* __restrict__ l2p, const int* __restrict__ start,
    const int* __restrict__ lenp, const int* __restrict__ order,
    const short* __restrict__ gth, const short* __restrict__ gtl,
    const float* __restrict__ bias, int n_paths, int n_waves)
{
    int tid = threadIdx.x;
    int warp = tid >> 6;
    int lane = tid & 63;
    int l15 = lane & 15, g = lane >> 4;

    int gw = blockIdx.x * 4 + warp;
    if (gw >= n_waves) return;
    int base16 = (n_waves - 1 - gw) * 16;     // longest chunks first (LPT by launch order)

    bf16x8 wKh[6], wKl[6], wRKh[6], wRKl[6];
    #pragma unroll
    for (int jt = 0; jt < 6; jt++){
        wKh[jt]  = *(const bf16x8*)(gth + ((size_t)((0 * 6 + jt) * 64 + lane)) * 8);
        wKl[jt]  = *(const bf16x8*)(gtl + ((size_t)((0 * 6 + jt) * 64 + lane)) * 8);
        wRKh[jt] = *(const bf16x8*)(gth + ((size_t)((1 * 6 + jt) * 64 + lane)) * 8);
        wRKl[jt] = *(const bf16x8*)(gtl + ((size_t)((1 * 6 + jt) * 64 + lane)) * 8);
    }
    f32x4 bZR[4], bXC[2], bHC[2];
    load_bias4(bias, g, bZR, bXC, bHC);

    int aidx = base16 + l15;
    bool va = (aidx < n_paths);
    int pa = order[min(aidx, n_paths - 1)];
    int s0 = start[pa];
    int la_c = lenp[pa];
    int la = va ? la_c : 0;
    int maxlen = __shfl(la_c, 15);

    float hD[2][4];
    {
        float4 h0 = *(const float4*)(ps + (size_t)pa * DD + 4 * g);
        float4 h1 = *(const float4*)(ps + (size_t)pa * DD + 16 + 4 * g);
        hD[0][0] = h0.x; hD[0][1] = h0.y; hD[0][2] = h0.z; hD[0][3] = h0.w;
        hD[1][0] = h1.x; hD[1][1] = h1.y; hD[1][2] = h1.z; hD[1][3] = h1.w;
    }

    bf16x8 hfh, hfl;
    hD_to_bfrag(hD, l15, g, hfh, hfl);

    bf16x8 xfh, xfl;
    {
        int lk = l2p[s0];
        xfh = *reinterpret_cast<const bf16x8*>(lsbh + (size_t)lk * DD + g * 8);
        xfl = *reinterpret_cast<const bf16x8*>(lsbl + (size_t)lk * DD + g * 8);
    }

    for (int t = 0; t < maxlen; ++t){
        bf16x8 nxh, nxl;
        int tn = t + 1;
        if (tn < maxlen){
            int e = s0 + max(min(tn, la - 1), 0);
            int lk = l2p[e];
            nxh = *reinterpret_cast<const bf16x8*>(lsbh + (size_t)lk * DD + g * 8);
            nxl = *reinterpret_cast<const bf16x8*>(lsbl + (size_t)lk * DD + g * 8);
        }

        f32x4 accZR[4], accXC[2], accHC[2];
        #pragma unroll
        for (int jt = 0; jt < 4; jt++){
            f32x4 a = bZR[jt];
            MFMA3(a, wKh[jt],  wKl[jt],  xfh, xfl);
            MFMA3(a, wRKh[jt], wRKl[jt], hfh, hfl);
            accZR[jt] = a;
        }
        #pragma unroll
        for (int u = 0; u < 2; u++){
            f32x4 ax = bXC[u];
            MFMA3(ax, wKh[4 + u], wKl[4 + u], xfh, xfl);
            accXC[u] = ax;
            f32x4 ah = bHC[u];
            MFMA3(ah, wRKh[4 + u], wRKl[4 + u], hfh, hfl);
            accHC[u] = ah;
        }

        gru_gates<true>(accZR, accXC, accHC, hD, la, t);
        hD_to_bfrag(hD, l15, g, hfh, hfl);

        xfh = nxh; xfl = nxl;
    }

    if (va){
        float4 h0 = { hD[0][0], hD[0][1], hD[0][2], hD[0][3] };
        float4 h1 = { hD[1][0], hD[1][1], hD[1][2], hD[1][3] };
        *(float4*)(ps + (size_t)pa * DD + 4 * g) = h0;
        *(float4*)(ps + (size_t)pa * DD + 16 + 4 * g) = h1;
    }
}

// ---------------- fused segment-sum + link GRU, 4-wave strided gather — R15, unchanged ----------------
__global__ __launch_bounds__(256, 1) void link_fused_kernel(
    const float* __restrict__ ps, const int* __restrict__ loff, const int* __restrict__ pbl,
    float* __restrict__ ls, short* __restrict__ lsbh, short* __restrict__ lsbl,
    const short* __restrict__ gth, const short* __restrict__ gtl,
    const float* __restrict__ bias, int n_links)
{
    __shared__ __align__(16) float part[3][16][36];

    int tid = threadIdx.x;
    int warp = tid >> 6;
    int lane = tid & 63;
    int l15 = lane & 15, g = lane >> 4;

    int base16 = blockIdx.x * 16;
    if (base16 >= n_links) return;

    int di = base16 + l15;
    bool va = (di < n_links);
    int pa = min(di, n_links - 1);

    float4 s0v = {0,0,0,0}, s1v = {0,0,0,0};
    {
        int b = loff[pa], e = loff[pa + 1];
        for (int k = b + warp; k < e; k += 4){
            const float4* pr = (const float4*)(ps + (size_t)pbl[k] * DD) + g * 2;
            float4 v0 = pr[0], v1 = pr[1];
            s0v.x += v0.x; s0v.y += v0.y; s0v.z += v0.z; s0v.w += v0.w;
            s1v.x += v1.x; s1v.y += v1.y; s1v.z += v1.z; s1v.w += v1.w;
        }
    }

    if (warp > 0){
        *(float4*)(&part[warp - 1][l15][g * 8])     = s0v;
        *(float4*)(&part[warp - 1][l15][g * 8 + 4]) = s1v;
    }
    __syncthreads();
    if (warp != 0) return;

    #pragma unroll
    for (int w = 0; w < 3; w++){
        float4 p0 = *(const float4*)(&part[w][l15][g * 8]);
        float4 p1 = *(const float4*)(&part[w][l15][g * 8 + 4]);
        s0v.x += p0.x; s0v.y += p0.y; s0v.z += p0.z; s0v.w += p0.w;
        s1v.x += p1.x; s1v.y += p1.y; s1v.z += p1.z; s1v.w += p1.w;
    }

    bf16x8 wKh[6], wKl[6], wRKh[6], wRKl[6];
    #pragma unroll
    for (int jt = 0; jt < 6; jt++){
        wKh[jt]  = *(const bf16x8*)(gth + ((size_t)((2 * 6 + jt) * 64 + lane)) * 8);
        wKl[jt]  = *(const bf16x8*)(gtl + ((size_t)((2 * 6 + jt) * 64 + lane)) * 8);
        wRKh[jt] = *(const bf16x8*)(gth + ((size_t)((3 * 6 + jt) * 64 + lane)) * 8);
        wRKl[jt] = *(const bf16x8*)(gtl + ((size_t)((3 * 6 + jt) * 64 + lane)) * 8);
    }
    f32x4 bZR[4], bXC[2], bHC[2];
    load_bias4(bias, g, bZR, bXC, bHC);

    float hD[2][4];
    {
        float4 h0 = *(const float4*)(ls + (size_t)pa * DD + 4 * g);
        float4 h1 = *(const float4*)(ls + (size_t)pa * DD + 16 + 4 * g);
        hD[0][0] = h0.x; hD[0][1] = h0.y; hD[0][2] = h0.z; hD[0][3] = h0.w;
        hD[1][0] = h1.x; hD[1][1] = h1.y; hD[1][2] = h1.z; hD[1][3] = h1.w;
    }
    bf16x8 hfh = *reinterpret_cast<const bf16x8*>(lsbh + (size_t)pa * DD + g * 8);
    bf16x8 hfl = *reinterpret_cast<const bf16x8*>(lsbl + (size_t)pa * DD + g * 8);

    bf16x8 xfh, xfl;
    {
        float xs[8] = { s0v.x, s0v.y, s0v.z, s0v.w, s1v.x, s1v.y, s1v.z, s1v.w };
        #pragma unroll
        for (int i = 0; i < 8; i++){
            short hi, lo; split2(xs[i], hi, lo);
            xfh[i] = hi; xfl[i] = lo;
        }
    }

    f32x4 accZR[4], accXC[2], accHC[2];
    #pragma unroll
    for (int jt = 0; jt < 4; jt++){
        f32x4 a = bZR[jt];
        MFMA3(a, wKh[jt],  wKl[jt],  xfh, xfl);
        MFMA3(a, wRKh[jt], wRKl[jt], hfh, hfl);
        accZR[jt] = a;
    }
    #pragma unroll
    for (int u = 0; u < 2; u++){
        f32x4 ax = bXC[u];
        MFMA3(ax, wKh[4 + u], wKl[4 + u], xfh, xfl);
        accXC[u] = ax;
        f32x4 ah = bHC[u];
        MFMA3(ah, wRKh[4 + u], wRKl[4 + u], hfh, hfl);
        accHC[u] = ah;
    }
    gru_gates<false>(accZR, accXC, accHC, hD, 0, 0);

    if (va){
        float4 h0 = { hD[0][0], hD[0][1], hD[0][2], hD[0][3] };
        float4 h1 = { hD[1][0], hD[1][1], hD[1][2], hD[1][3] };
        *(float4*)(ls + (size_t)pa * DD + 4 * g) = h0;
        *(float4*)(ls + (size_t)pa * DD + 16 + 4 * g) = h1;
        short hs[8], lws[8];
        #pragma unroll
        for (int r = 0; r < 4; r++){ split2(hD[0][r], hs[r], lws[r]); split2(hD[1][r], hs[4 + r], lws[4 + r]); }
        *(short4*)(lsbh + (size_t)pa * DD + 4 * g)      = make_short4(hs[0], hs[1], hs[2], hs[3]);
        *(short4*)(lsbh + (size_t)pa * DD + 16 + 4 * g) = make_short4(hs[4], hs[5], hs[6], hs[7]);
        *(short4*)(lsbl + (size_t)pa * DD + 4 * g)      = make_short4(lws[0], lws[1], lws[2], lws[3]);
        *(short4*)(lsbl + (size_t)pa * DD + 16 + 4 * g) = make_short4(lws[4], lws[5], lws[6], lws[7]);
    }
}

// ---------------- readout MLP (MFMA split-bf16): 32 -> 256 relu -> 256 relu -> 1 ----------------
// R15 version restored: 64 paths/block, VGPR 76, 26% occupancy, 94 us.
// (R16's 2x weight-reuse variant REGRESSED to 120 us: VGPR 148 / LDS 34KB dropped
// occupancy to 9% -> latency-bound, not L2-BW bound. Keep the high-occupancy form.)
__global__ __launch_bounds__(256) void readout_kernel(
    const float* __restrict__ ps,
    const short* __restrict__ rth, const short* __restrict__ rtl,
    const float* __restrict__ b1, const float* __restrict__ b2,
    const float* __restrict__ w3, const float* __restrict__ b3,
    float* __restrict__ out, int n_paths)
{
    __shared__ __align__(16) float hT[4][16 * 68];

    int tid = threadIdx.x;
    int warp = tid >> 6;
    int lane = tid & 63;
    int l15 = lane & 15, g = lane >> 4;
    int pbase = blockIdx.x * 64 + warp * 16;

    bf16x8 xh, xl;
    {
        int prow = min(pbase + l15, n_paths - 1);
        const float* xp = ps + (size_t)prow * DD + g * 8;
        #pragma unroll
        for (int i = 0; i < 8; i++){ short hi, lo; split2(xp[i], hi, lo); xh[i] = hi; xl[i] = lo; }
    }

    float* hw = hT[warp];

    f32x4 acc2[16];
    #pragma unroll
    for (int jt = 0; jt < 16; jt++) acc2[jt] = splat4(b2[jt * 16 + l15]);

    #pragma unroll 1
    for (int c = 0; c < 4; c++){
        #pragma unroll
        for (int u = 0; u < 4; u++){
            int jt = c * 4 + u;
            bf16x8 wh = *(const bf16x8*)(rth + (size_t)(jt * 64 + lane) * 8);
            bf16x8 wl = *(const bf16x8*)(rtl + (size_t)(jt * 64 + lane) * 8);
            f32x4 a = splat4(b1[jt * 16 + l15]);
            MFMA3(a, xh, xl, wh, wl);
            #pragma unroll
            for (int r = 0; r < 4; r++)
                hw[(g * 4 + r) * 68 + u * 16 + l15] = fmaxf(a[r], 0.0f);
        }
        bf16x8 ah[2], al[2];
        #pragma unroll
        for (int kc2 = 0; kc2 < 2; kc2++){
            const float* hr = hw + l15 * 68 + kc2 * 32 + g * 8;
            #pragma unroll
            for (int i = 0; i < 8; i++){ short hi, lo; split2(hr[i], hi, lo); ah[kc2][i] = hi; al[kc2][i] = lo; }
        }
        #pragma unroll
        for (int jt = 0; jt < 16; jt++){
            #pragma unroll
            for (int kc2 = 0; kc2 < 2; kc2++){
                int f = 16 + (c * 2 + kc2) * 16 + jt;
                bf16x8 wh = *(const bf16x8*)(rth + (size_t)(f * 64 + lane) * 8);
                bf16x8 wl = *(const bf16x8*)(rtl + (size_t)(f * 64 + lane) * 8);
                MFMA3(acc2[jt], ah[kc2], al[kc2], wh, wl);
            }
        }
    }

    float part[4] = {0.0f, 0.0f, 0.0f, 0.0f};
    #pragma unroll
    for (int jt = 0; jt < 16; jt++){
        float w3v = w3[jt * 16 + l15];
        #pragma unroll
        for (int r = 0; r < 4; r++)
            part[r] = fmaf(fmaxf(acc2[jt][r], 0.0f), w3v, part[r]);
    }
    #pragma unroll
    for (int ofs = 1; ofs < 16; ofs <<= 1)
        #pragma unroll
        for (int r = 0; r < 4; r++)
            part[r] += __shfl_xor(part[r], ofs);

    if (l15 == 0){
        float b3v = b3[0];
        #pragma unroll
        for (int r = 0; r < 4; r++){
            int p = pbase + g * 4 + r;
            if (p < n_paths) out[p] = part[r] + b3v;
        }
    }
}

extern "C" void kernel_launch(void* const* d_in, const int* in_sizes, int n_in,
                              void* d_out, int out_size, void* d_ws, size_t ws_size,
                              hipStream_t stream)
{
    const float* capacity = (const float*)d_in[0];
    const float* traffic  = (const float*)d_in[1];
    const float* packets  = (const float*)d_in[2];
    const float* tdp      = (const float*)d_in[3];
    const float* pK  = (const float*)d_in[4];
    const float* pRK = (const float*)d_in[5];
    const float* pB  = (const float*)d_in[6];
    const float* lK  = (const float*)d_in[7];
    const float* lRK = (const float*)d_in[8];
    const float* lB  = (const float*)d_in[9];
    const float* w1  = (const float*)d_in[10];
    const float* b1  = (const float*)d_in[11];
    const float* w2  = (const float*)d_in[12];
    const float* b2  = (const float*)d_in[13];
    const float* w3  = (const float*)d_in[14];
    const float* b3  = (const float*)d_in[15];
    const int* l2p      = (const int*)d_in[16];
    const int* path_ids = (const int*)d_in[17];
    const int* seqp     = (const int*)d_in[18];
    const int* p2l      = (const int*)d_in[19];
    const int* seql     = (const int*)d_in[20];
    int n_links = in_sizes[0];
    int n_paths = in_sizes[1];
    int E       = in_sizes[16];
    float* out = (float*)d_out;

    char* w = (char*)d_ws;
    auto carve = [&](size_t bytes) -> void* {
        void* r = (void*)w;
        w += (bytes + 255) & ~(size_t)255;
        return r;
    };
    int nblk = (n_paths + 255) / 256;
    float* ls    = (float*)carve((size_t)n_links * DD * 4);
    short* lsbh  = (short*)carve((size_t)n_links * DD * 2);
    short* lsbl  = (short*)carve((size_t)n_links * DD * 2);
    float* ps    = (float*)carve((size_t)n_paths * DD * 4);
    int* start   = (int*)carve((size_t)n_paths * 4);
    int* lenp    = (int*)carve((size_t)n_paths * 4);
    int* order   = (int*)carve((size_t)n_paths * 4);
    int* loff    = (int*)carve((size_t)(n_links + 1) * 4);
    int* pbl     = (int*)carve((size_t)E * 4);
    short* gth   = (short*)carve((size_t)4 * 6 * 64 * 8 * 2);
    short* gtl   = (short*)carve((size_t)4 * 6 * 64 * 8 * 2);
    short* rth   = (short*)carve((size_t)144 * 64 * 8 * 2);
    short* rtl   = (short*)carve((size_t)144 * 64 * 8 * 2);
    int* bh      = (int*)carve((size_t)nblk * 16 * 4);
    int* bb      = (int*)carve((size_t)nblk * 16 * 4);
    int* izero   = (int*)carve(((size_t)2 * n_links + 16) * 4);
    int* lcount  = izero;
    int* lfill   = izero + n_links;
    int* bcnt    = izero + 2 * n_links;

    const int TB = 256;
    int nz = 2 * n_links + 16;
    zero_ints_kernel<<<(nz + TB - 1) / TB, TB, 0, stream>>>(izero, nz);
    init_states_kernel<<<(((n_links + n_paths) * DD) + TB - 1) / TB, TB, 0, stream>>>(
        capacity, traffic, packets, tdp, ls, lsbh, lsbl, ps, n_links, n_paths);
    meta_kernel<<<(E + TB - 1) / TB, TB, 0, stream>>>(path_ids, seqp, seql, start, lenp, lcount, E);
    bhist_block_kernel<<<nblk, 256, 0, stream>>>(lenp, bcnt, bh, n_paths);
    bscan2_kernel<<<1, 64, 0, stream>>>(bcnt, bh, bb, nblk);
    bscatter2_kernel<<<nblk, 256, 0, stream>>>(lenp, bb, order, n_paths);
    scan_kernel<<<1, 1024, 0, stream>>>(lcount, loff, n_links);
    fillpbl_kernel<<<(E + TB - 1) / TB, TB, 0, stream>>>(seql, p2l, loff, lfill, pbl, E);
    pack_all_kernel<<<((4 * 6 * 64 + 144 * 64) + TB - 1) / TB, TB, 0, stream>>>(
        pK, pRK, lK, lRK, w1, w2, gth, gtl, rth, rtl);

    int n_waves = (n_paths + 15) / 16;
    int pg_blocks = (n_waves + 3) / 4;
    int lg_blocks = (n_links + 15) / 16;      // one block (4 waves) per 16 links

    for (int it = 0; it < 8; ++it){
        path_gru_kernel<<<pg_blocks, 256, 0, stream>>>(lsbh, lsbl, ps, l2p, start, lenp, order,
                                                       gth, gtl, pB, n_paths, n_waves);
        link_fused_kernel<<<lg_blocks, 256, 0, stream>>>(ps, loff, pbl, ls, lsbh, lsbl,
                                                         gth, gtl, lB, n_links);
    }
    readout_kernel<<<(n_paths + 63) / 64, 256, 0, stream>>>(ps, rth, rtl, b1, b2, w3, b3, out, n_paths);
}